// Round 7
// baseline (573.742 us; speedup 1.0000x reference)
//
#include <hip/hip_runtime.h>
#include <hip/hip_bf16.h>

// Flash attention fwd, masked, fp32 I/O, bf16 MFMA compute.
// n=8 heads, q=s=4096, d=v=64.
// S^T = K·Q^T (lane owns one q-column); PV computes O^T = V^T·P^T.
// Round 7: s-split — each q-tile processed by TWO waves (s-halves),
// merged in LDS at the end. 512-thread blocks, 80KB LDS, 2 blocks/CU
// -> 16 waves/CU (was 8). Mask path is a template param (dead regs
// eliminated); defer-max rescale skip; setprio around MFMA clusters.

#define NHEADS 8
#define QLEN   4096
#define SLEN   4096
#define DDIM   64
#define VDIM   64
#define SBLK   64
#define QBLK   64
#define NSTEP  32          // chunks per s-half
#define QSTRIDE 20         // merge-area q stride (2-way bank conflicts only)

typedef __bf16          bf16x4 __attribute__((ext_vector_type(4)));
typedef __bf16          bf16x8 __attribute__((ext_vector_type(8)));
typedef float           f32x4  __attribute__((ext_vector_type(4)));
typedef unsigned int    u32x4  __attribute__((ext_vector_type(4)));
typedef unsigned short  u16x4  __attribute__((ext_vector_type(4)));

#define KSWZ(s) (((s) & 7) << 4)
#define VSWZ(v) ((((v) >> 2) & 7) << 4)

// ---------------- in-kernel mask dtype detection ----------------
// Wave-cooperative scan of the mask's first 1KB (64 lanes x 16B).
// i32 {0,1}: bytes 1,2 of every word zero -> 1.
// f32 {0,1.0f}: byte 0 of every word zero (0x3F800000 LE) -> 2.
// u8 bool: neither -> 0. Uniform across all lanes/waves/blocks.
__device__ __forceinline__ int detect_mfmt(const unsigned char* __restrict__ M) {
  const int lane = threadIdx.x & 63;
  u32x4 w = *((const u32x4*)M + lane);
  unsigned o = w[0] | w[1] | w[2] | w[3];
  unsigned comb = ((o & 0x00FFFF00u) ? 1u : 0u) | ((o & 0x000000FFu) ? 2u : 0u);
  comb |= __shfl_xor((int)comb, 1);  comb |= __shfl_xor((int)comb, 2);
  comb |= __shfl_xor((int)comb, 4);  comb |= __shfl_xor((int)comb, 8);
  comb |= __shfl_xor((int)comb, 16); comb |= __shfl_xor((int)comb, 32);
  return ((comb & 1u) == 0u) ? 1 : (((comb & 2u) == 0u) ? 2 : 0);
}

template<bool U8>
__global__ __launch_bounds__(512, 4)
void attn_fwd(const float* __restrict__ Qg, const float* __restrict__ Kg,
              const float* __restrict__ Vg, const unsigned char* __restrict__ Mg,
              float* __restrict__ Og)
{
  __shared__ __align__(16) unsigned short Ksh[2][2][64 * 64];   // [half][buf][s][d]
  __shared__ __align__(16) unsigned short Vsh[2][2][64 * 64];   // [half][buf][v][s]
  __shared__ __align__(16) unsigned short Psh[8][16 * 64];      // per wave [q][s]

  {
    const int mfmt = detect_mfmt(Mg);
    if (U8 ? (mfmt != 0) : (mfmt == 0)) return;   // other instantiation handles it
  }

  const int tid  = threadIdx.x;
  const int wave = tid >> 6;
  const int lane = tid & 63;
  const int g    = lane >> 4;
  const int lq   = lane & 15;
  const int half = wave >> 2;     // s-half this wave owns
  const int wq   = wave & 3;      // q-tile this wave owns
  const int hid  = tid & 255;     // staging index within the half's 256 threads

  const int head = blockIdx.x;    // grid (8, 64): linear id % 8 == head -> one XCD per head
  const int qblk = blockIdx.y;

  const float* Qp = Qg + ((size_t)head * QLEN + (size_t)qblk * QBLK) * DDIM;
  const float* Kp = Kg + (size_t)head * SLEN * DDIM + (size_t)half * NSTEP * SBLK * DDIM;
  const float* Vp = Vg + (size_t)head * SLEN * VDIM + (size_t)half * NSTEP * SBLK * VDIM;
  float* Op = Og + ((size_t)head * QLEN + (size_t)qblk * QBLK) * DDIM;

  // Q fragments, pre-scaled by (1/sqrt(d))*log2(e)
  const float QSCALE = 0.125f * 1.44269504f;
  const int qrow = wq * 16 + lq;
  bf16x8 qf[2];
#pragma unroll
  for (int ks = 0; ks < 2; ++ks) {
    const float* qp = Qp + (size_t)qrow * DDIM + 8 * g + 32 * ks;
    f32x4 a = *(const f32x4*)qp;
    f32x4 b = *(const f32x4*)(qp + 4);
    bf16x8 t;
#pragma unroll
    for (int j = 0; j < 4; ++j) { t[j] = (__bf16)(a[j] * QSCALE); t[4 + j] = (__bf16)(b[j] * QSCALE); }
    qf[ks] = t;
  }

  const size_t mbase = ((size_t)head * QLEN + (size_t)qblk * QBLK + qrow) * SLEN;
  const unsigned char* mrow8  = Mg + mbase + (size_t)half * NSTEP * SBLK;
  const unsigned*      mrow32 = (const unsigned*)Mg + mbase + (size_t)half * NSTEP * SBLK;

  f32x4 oacc[4];
#pragma unroll
  for (int vt = 0; vt < 4; ++vt) oacc[vt] = (f32x4){0.f, 0.f, 0.f, 0.f};
  float m_run = -INFINITY;
  float l_run = 0.f;

  unsigned m8A[4],  m8B[4];     // only the U8 set is live (template DCE)
  u32x4    m32A[4], m32B[4];

#define PREFETCH_KV(STEPN)                                                     \
  _Pragma("unroll")                                                            \
  for (int it = 0; it < 4; ++it) {                                             \
    int srow = (hid >> 4) + it * 16;                                           \
    int d0   = (hid & 15) * 4;                                                 \
    kpre[it] = *(const f32x4*)(Kp + (size_t)((STEPN) * SBLK + srow) * DDIM + d0); \
    vpre[it] = *(const f32x4*)(Vp + (size_t)((STEPN) * SBLK + srow) * VDIM + d0); \
  }

#define WRITE_KV(BUF)                                                          \
  _Pragma("unroll")                                                            \
  for (int it = 0; it < 4; ++it) {                                             \
    int srow = (hid >> 4) + it * 16;                                           \
    int d0   = (hid & 15) * 4;                                                 \
    bf16x4 kb;                                                                 \
    _Pragma("unroll") for (int j = 0; j < 4; ++j) kb[j] = (__bf16)kpre[it][j]; \
    int koff = (srow * 128 + d0 * 2) ^ KSWZ(srow);                             \
    *(u16x4*)((char*)Ksh[half][BUF] + koff) = __builtin_bit_cast(u16x4, kb);   \
    _Pragma("unroll")                                                          \
    for (int j = 0; j < 4; ++j) {                                              \
      int v = d0 + j;                                                          \
      unsigned short b = __builtin_bit_cast(unsigned short, (__bf16)vpre[it][j]); \
      int voff = (v * 128 + srow * 2) ^ VSWZ(v);                               \
      *(unsigned short*)((char*)Vsh[half][BUF] + voff) = b;                    \
    }                                                                          \
  }

#define LOAD_MASK(M8, M32, S0)                                                 \
  if constexpr (U8) {                                                          \
    _Pragma("unroll")                                                          \
    for (int st = 0; st < 4; ++st)                                             \
      M8[st] = *(const unsigned*)(mrow8 + (S0) + 16 * st + 4 * g);             \
  } else {                                                                     \
    _Pragma("unroll")                                                          \
    for (int st = 0; st < 4; ++st)                                             \
      M32[st] = *(const u32x4*)(mrow32 + (S0) + 16 * st + 4 * g);              \
  }

#define CHUNK_BODY(STEP, CUR, MU8, MU32, ML8, ML32) {                          \
  const bool hasn = ((STEP) + 1 < NSTEP);                                      \
  f32x4 kpre[4]; f32x4 vpre[4];                                                \
  if (hasn) {                                                                  \
    PREFETCH_KV((STEP) + 1);                                                   \
    LOAD_MASK(ML8, ML32, ((STEP) + 1) * SBLK);                                 \
  }                                                                            \
  /* QK^T: S^T tiles (A = K rows-of-s, B = Q^T) */                             \
  f32x4 sacc[4];                                                               \
  _Pragma("unroll")                                                            \
  for (int st = 0; st < 4; ++st) sacc[st] = (f32x4){0.f, 0.f, 0.f, 0.f};       \
  __builtin_amdgcn_s_setprio(1);                                               \
  _Pragma("unroll")                                                            \
  for (int st = 0; st < 4; ++st) {                                             \
    int srow = lq + 16 * st;                                                   \
    _Pragma("unroll")                                                          \
    for (int ks = 0; ks < 2; ++ks) {                                           \
      int off = (srow * 128 + (8 * g + 32 * ks) * 2) ^ KSWZ(srow);             \
      bf16x8 kf = *(const bf16x8*)((const char*)Ksh[half][CUR] + off);         \
      sacc[st] = __builtin_amdgcn_mfma_f32_16x16x32_bf16(kf, qf[ks], sacc[st], 0, 0, 0); \
    }                                                                          \
  }                                                                            \
  __builtin_amdgcn_s_setprio(0);                                               \
  /* mask + chunk max (lane scores: s = 16st+4g+r, q=lq) */                    \
  float vals[4][4];                                                            \
  float mloc = -INFINITY;                                                      \
  _Pragma("unroll")                                                            \
  for (int st = 0; st < 4; ++st) {                                             \
    bool keep[4];                                                              \
    if constexpr (U8) {                                                        \
      _Pragma("unroll")                                                        \
      for (int r = 0; r < 4; ++r) keep[r] = ((MU8[st] >> (8 * r)) & 0xFFu) != 0u; \
    } else {                                                                   \
      _Pragma("unroll")                                                        \
      for (int r = 0; r < 4; ++r) keep[r] = MU32[st][r] != 0u;                 \
    }                                                                          \
    _Pragma("unroll")                                                          \
    for (int r = 0; r < 4; ++r) {                                              \
      float v = keep[r] ? sacc[st][r] : -1.0e9f;                               \
      vals[st][r] = v;                                                         \
      mloc = fmaxf(mloc, v);                                                   \
    }                                                                          \
  }                                                                            \
  mloc = fmaxf(mloc, __shfl_xor(mloc, 16));                                    \
  mloc = fmaxf(mloc, __shfl_xor(mloc, 32));                                    \
  /* defer-max: rescale only if some row's max grew by > 8 (log2 domain) */    \
  if (!__all(mloc <= m_run + 8.0f)) {                                          \
    float m_new = fmaxf(m_run, mloc);                                          \
    float alpha = __builtin_amdgcn_exp2f(m_run - m_new);                       \
    l_run *= alpha;                                                            \
    _Pragma("unroll")                                                          \
    for (int vt = 0; vt < 4; ++vt) {                                           \
      _Pragma("unroll")                                                        \
      for (int r = 0; r < 4; ++r) oacc[vt][r] *= alpha;                        \
    }                                                                          \
    m_run = m_new;                                                             \
  }                                                                            \
  float lsum = 0.f;                                                            \
  _Pragma("unroll")                                                            \
  for (int st = 0; st < 4; ++st) {                                             \
    bf16x4 pb;                                                                 \
    _Pragma("unroll")                                                          \
    for (int r = 0; r < 4; ++r) {                                              \
      float p = __builtin_amdgcn_exp2f(vals[st][r] - m_run);                   \
      lsum += p;                                                               \
      pb[r] = (__bf16)p;                                                       \
    }                                                                          \
    int off = (lq * 128 + (16 * st + 4 * g) * 2) ^ KSWZ(lq);                   \
    *(u16x4*)((char*)Psh[wave] + off) = __builtin_bit_cast(u16x4, pb);         \
  }                                                                            \
  lsum += __shfl_xor(lsum, 16);                                                \
  lsum += __shfl_xor(lsum, 32);                                                \
  l_run += lsum;                                                               \
  /* PV: O^T += V^T_tile · P^T */                                              \
  __builtin_amdgcn_s_setprio(1);                                               \
  _Pragma("unroll")                                                            \
  for (int ks = 0; ks < 2; ++ks) {                                             \
    int poff = (lq * 128 + (8 * g + 32 * ks) * 2) ^ KSWZ(lq);                  \
    bf16x8 pf = *(const bf16x8*)((const char*)Psh[wave] + poff);               \
    _Pragma("unroll")                                                          \
    for (int vt = 0; vt < 4; ++vt) {                                           \
      int vrow = lq + 16 * vt;                                                 \
      int voff = (vrow * 128 + (8 * g + 32 * ks) * 2) ^ VSWZ(vrow);            \
      bf16x8 vf = *(const bf16x8*)((const char*)Vsh[half][CUR] + voff);        \
      oacc[vt] = __builtin_amdgcn_mfma_f32_16x16x32_bf16(vf, pf, oacc[vt], 0, 0, 0); \
    }                                                                          \
  }                                                                            \
  __builtin_amdgcn_s_setprio(0);                                               \
  if (hasn) { WRITE_KV((CUR) ^ 1); }                                           \
  __syncthreads();                                                             \
}

  // prologue: both halves stage their step-0 chunk
  {
    f32x4 kpre[4]; f32x4 vpre[4];
    PREFETCH_KV(0);
    LOAD_MASK(m8A, m32A, 0);
    WRITE_KV(0);
    __syncthreads();
  }

  for (int ss = 0; ss < NSTEP; ss += 2) {
    CHUNK_BODY(ss,     0, m8A, m32A, m8B, m32B);
    CHUNK_BODY(ss + 1, 1, m8B, m32B, m8A, m32A);
  }

  // ---- merge the two s-halves via LDS (K/V buffers are dead now) ----
  float* mO = (float*)&Ksh[0][0][0];   // [wq][64 v][QSTRIDE] floats (20480 B)
  float* mM = (float*)&Vsh[0][0][0];   // [wq][2][16]: m then l      (512 B)
  __syncthreads();
  if (half == 1) {
#pragma unroll
    for (int vt = 0; vt < 4; ++vt) {
#pragma unroll
      for (int r = 0; r < 4; ++r)
        mO[((size_t)wq * 64 + 16 * vt + 4 * g + r) * QSTRIDE + lq] = oacc[vt][r];
    }
    if (g == 0) {
      mM[(wq * 2 + 0) * 16 + lq] = m_run;
      mM[(wq * 2 + 1) * 16 + lq] = l_run;
    }
  }
  __syncthreads();
  if (half == 0) {
    float m1 = mM[(wq * 2 + 0) * 16 + lq];
    float l1 = mM[(wq * 2 + 1) * 16 + lq];
    float mm = fmaxf(m_run, m1);
    float a0 = __builtin_amdgcn_exp2f(m_run - mm);
    float a1 = __builtin_amdgcn_exp2f(m1 - mm);
    float inv = 1.0f / (l_run * a0 + l1 * a1);
    float* orow = Op + (size_t)qrow * VDIM;
#pragma unroll
    for (int vt = 0; vt < 4; ++vt) {
      f32x4 o;
#pragma unroll
      for (int r = 0; r < 4; ++r) {
        float o1 = mO[((size_t)wq * 64 + 16 * vt + 4 * g + r) * QSTRIDE + lq];
        o[r] = (oacc[vt][r] * a0 + o1 * a1) * inv;
      }
      *(f32x4*)(orow + 16 * vt + 4 * g) = o;
    }
  }
#undef PREFETCH_KV
#undef WRITE_KV
#undef LOAD_MASK
#undef CHUNK_BODY
}

extern "C" void kernel_launch(void* const* d_in, const int* in_sizes, int n_in,
                              void* d_out, int out_size, void* d_ws, size_t ws_size,
                              hipStream_t stream) {
  const float* Qg = (const float*)d_in[0];
  const float* Kg = (const float*)d_in[1];
  const float* Vg = (const float*)d_in[2];
  const unsigned char* Mg = (const unsigned char*)d_in[3];
  float* Og = (float*)d_out;

  dim3 grid(NHEADS, QLEN / QBLK);   // linear id % 8 == head -> head-per-XCD
  dim3 block(512);
  attn_fwd<true ><<<grid, block, 0, stream>>>(Qg, Kg, Vg, Mg, Og);   // u8 bool mask
  attn_fwd<false><<<grid, block, 0, stream>>>(Qg, Kg, Vg, Mg, Og);   // i32/f32 mask
}

// Round 8
// 147.983 us; speedup vs baseline: 3.8771x; 3.8771x over previous
//
#include <hip/hip_runtime.h>
#include <hip/hip_bf16.h>

// Flash attention fwd, masked, fp32 I/O, bf16 MFMA compute.
// n=8 heads, q=s=4096, d=v=64.
// S^T = K·Q^T (lane owns one q-column); PV computes O^T = V^T·P^T.
// Round 8: r6 structure + (a) QBLK=128 / 512-thread blocks
// (__launch_bounds__(512,2): 256-VGPR cap — r7's (512,4) forced 64 VGPR and
// spilled ~1.8GB of scratch), halving per-CU K/V staging + L2 traffic;
// (b) prefetch distance 2 (two named reg sets): WRITE_KV drains loads issued
// one full body earlier, so L2/HBM latency hides under a whole chunk.

#define NHEADS 8
#define QLEN   4096
#define SLEN   4096
#define DDIM   64
#define VDIM   64
#define SBLK   64
#define QBLK   128
#define NWAVES 8
#define NCHUNK (SLEN / SBLK)

typedef __bf16          bf16x4 __attribute__((ext_vector_type(4)));
typedef __bf16          bf16x8 __attribute__((ext_vector_type(8)));
typedef float           f32x4  __attribute__((ext_vector_type(4)));
typedef unsigned int    u32x4  __attribute__((ext_vector_type(4)));
typedef unsigned short  u16x4  __attribute__((ext_vector_type(4)));

#define KSWZ(s) (((s) & 7) << 4)
#define VSWZ(v) ((((v) >> 2) & 7) << 4)
#define CLAMPC(c) ((c) < NCHUNK ? (c) : NCHUNK - 1)

// ---------------- in-kernel mask dtype detection ----------------
// Wave-cooperative scan of the mask's first 1KB (64 lanes x 16B).
// i32 {0,1}: bytes 1,2 of every word zero -> 1.
// f32 {0,1.0f}: byte 0 of every word zero (0x3F800000 LE) -> 2.
// u8 bool: neither -> 0. Uniform across all lanes/waves/blocks.
__device__ __forceinline__ int detect_mfmt(const unsigned char* __restrict__ M) {
  const int lane = threadIdx.x & 63;
  u32x4 w = *((const u32x4*)M + lane);
  unsigned o = w[0] | w[1] | w[2] | w[3];
  unsigned comb = ((o & 0x00FFFF00u) ? 1u : 0u) | ((o & 0x000000FFu) ? 2u : 0u);
  comb |= __shfl_xor((int)comb, 1);  comb |= __shfl_xor((int)comb, 2);
  comb |= __shfl_xor((int)comb, 4);  comb |= __shfl_xor((int)comb, 8);
  comb |= __shfl_xor((int)comb, 16); comb |= __shfl_xor((int)comb, 32);
  return ((comb & 1u) == 0u) ? 1 : (((comb & 2u) == 0u) ? 2 : 0);
}

template<bool U8>
__global__ __launch_bounds__(512, 2)
void attn_fwd(const float* __restrict__ Qg, const float* __restrict__ Kg,
              const float* __restrict__ Vg, const unsigned char* __restrict__ Mg,
              float* __restrict__ Og)
{
  __shared__ __align__(16) unsigned short Ksh[2][64 * 64];       // [buf][s][d], KSWZ rows
  __shared__ __align__(16) unsigned short Vsh[2][64 * 64];       // [buf][v][s], VSWZ rows
  __shared__ __align__(16) unsigned short Psh[NWAVES][16 * 64];  // [q][s] per wave

  {
    const int mfmt = detect_mfmt(Mg);
    if (U8 ? (mfmt != 0) : (mfmt == 0)) return;   // other instantiation handles it
  }

  const int tid  = threadIdx.x;
  const int wave = tid >> 6;
  const int lane = tid & 63;
  const int g    = lane >> 4;
  const int lq   = lane & 15;

  const int head = blockIdx.x;    // grid (8, 32): linear id % 8 == head -> one XCD per head
  const int qblk = blockIdx.y;

  const float* Qp = Qg + ((size_t)head * QLEN + (size_t)qblk * QBLK) * DDIM;
  const float* Kp = Kg + (size_t)head * SLEN * DDIM;
  const float* Vp = Vg + (size_t)head * SLEN * VDIM;
  float* Op = Og + ((size_t)head * QLEN + (size_t)qblk * QBLK) * DDIM;

  // Q fragments, pre-scaled by (1/sqrt(d))*log2(e)
  const float QSCALE = 0.125f * 1.44269504f;
  const int qrow = wave * 16 + lq;          // 0..127 within the q-block
  bf16x8 qf[2];
#pragma unroll
  for (int ks = 0; ks < 2; ++ks) {
    const float* qp = Qp + (size_t)qrow * DDIM + 8 * g + 32 * ks;
    f32x4 a = *(const f32x4*)qp;
    f32x4 b = *(const f32x4*)(qp + 4);
    bf16x8 t;
#pragma unroll
    for (int j = 0; j < 4; ++j) { t[j] = (__bf16)(a[j] * QSCALE); t[4 + j] = (__bf16)(b[j] * QSCALE); }
    qf[ks] = t;
  }

  const size_t mrow_elems = ((size_t)head * QLEN + (size_t)qblk * QBLK + qrow) * SLEN;
  const unsigned char* mrow8  = Mg + mrow_elems;
  const unsigned*      mrow32 = (const unsigned*)Mg + mrow_elems;

  f32x4 oacc[4];
#pragma unroll
  for (int vt = 0; vt < 4; ++vt) oacc[vt] = (f32x4){0.f, 0.f, 0.f, 0.f};
  float m_run = -INFINITY;
  float l_run = 0.f;

  // two named prefetch reg sets (rule #20: no runtime-indexed reg arrays)
  f32x4 kpA[2], vpA[2], kpB[2], vpB[2];
  unsigned m8A[4],  m8B[4];     // only the U8 set is live (template DCE)
  u32x4    m32A[4], m32B[4];

  // 512 threads stage the 64x64 chunk in 2 passes: srow=(tid>>4)+32it, d0=(tid&15)*4
#define PREFETCH_KV(C, KP, VP)                                                 \
  _Pragma("unroll")                                                            \
  for (int it = 0; it < 2; ++it) {                                             \
    int srow = (tid >> 4) + it * 32;                                           \
    int d0   = (tid & 15) * 4;                                                 \
    size_t gs = (size_t)(CLAMPC(C) * SBLK + srow);                             \
    KP[it] = *(const f32x4*)(Kp + gs * DDIM + d0);                             \
    VP[it] = *(const f32x4*)(Vp + gs * VDIM + d0);                             \
  }

  // K: b64 row writes (KSWZ). V: transposed scatter, 8x b16 (VSWZ -> ~4-way).
#define WRITE_KV(BUF, KP, VP)                                                  \
  _Pragma("unroll")                                                            \
  for (int it = 0; it < 2; ++it) {                                             \
    int srow = (tid >> 4) + it * 32;                                           \
    int d0   = (tid & 15) * 4;                                                 \
    bf16x4 kb;                                                                 \
    _Pragma("unroll") for (int j = 0; j < 4; ++j) kb[j] = (__bf16)KP[it][j];   \
    int koff = (srow * 128 + d0 * 2) ^ KSWZ(srow);                             \
    *(u16x4*)((char*)Ksh[BUF] + koff) = __builtin_bit_cast(u16x4, kb);         \
    _Pragma("unroll")                                                          \
    for (int j = 0; j < 4; ++j) {                                              \
      int v = d0 + j;                                                          \
      unsigned short b = __builtin_bit_cast(unsigned short, (__bf16)VP[it][j]); \
      int voff = (v * 128 + srow * 2) ^ VSWZ(v);                               \
      *(unsigned short*)((char*)Vsh[BUF] + voff) = b;                          \
    }                                                                          \
  }

#define LOAD_MASK(M8, M32, C)                                                  \
  if constexpr (U8) {                                                          \
    _Pragma("unroll")                                                          \
    for (int st = 0; st < 4; ++st)                                             \
      M8[st] = *(const unsigned*)(mrow8 + (size_t)CLAMPC(C) * SBLK + 16 * st + 4 * g); \
  } else {                                                                     \
    _Pragma("unroll")                                                          \
    for (int st = 0; st < 4; ++st)                                             \
      M32[st] = *(const u32x4*)(mrow32 + (size_t)CLAMPC(C) * SBLK + 16 * st + 4 * g); \
  }

// Body C: buf[CUR] ready; (KPW,VPW) hold chunk C+1 (loads issued at body C-1);
// (KPF,VPF) are free -> receive prefetch(C+2). Mask set (M8U,M32U) holds mask C,
// reloaded with mask C+2 right after its use.
#define CHUNK_BODY(C, CUR, KPF, VPF, KPW, VPW, M8U, M32U) {                    \
  PREFETCH_KV((C) + 2, KPF, VPF);                                              \
  /* QK^T: S^T tiles (A = K rows-of-s, B = Q^T) */                             \
  f32x4 sacc[4];                                                               \
  _Pragma("unroll")                                                            \
  for (int st = 0; st < 4; ++st) sacc[st] = (f32x4){0.f, 0.f, 0.f, 0.f};       \
  __builtin_amdgcn_s_setprio(1);                                               \
  _Pragma("unroll")                                                            \
  for (int st = 0; st < 4; ++st) {                                             \
    int srow = lq + 16 * st;                                                   \
    _Pragma("unroll")                                                          \
    for (int ks = 0; ks < 2; ++ks) {                                           \
      int off = (srow * 128 + (8 * g + 32 * ks) * 2) ^ KSWZ(srow);             \
      bf16x8 kf = *(const bf16x8*)((const char*)Ksh[CUR] + off);               \
      sacc[st] = __builtin_amdgcn_mfma_f32_16x16x32_bf16(kf, qf[ks], sacc[st], 0, 0, 0); \
    }                                                                          \
  }                                                                            \
  __builtin_amdgcn_s_setprio(0);                                               \
  /* mask + chunk max (lane scores: s = 16st+4g+r, q=lq) */                    \
  float vals[4][4];                                                            \
  float mloc = -INFINITY;                                                      \
  _Pragma("unroll")                                                            \
  for (int st = 0; st < 4; ++st) {                                             \
    bool keep[4];                                                              \
    if constexpr (U8) {                                                        \
      _Pragma("unroll")                                                        \
      for (int r = 0; r < 4; ++r) keep[r] = ((M8U[st] >> (8 * r)) & 0xFFu) != 0u; \
    } else {                                                                   \
      _Pragma("unroll")                                                        \
      for (int r = 0; r < 4; ++r) keep[r] = M32U[st][r] != 0u;                 \
    }                                                                          \
    _Pragma("unroll")                                                          \
    for (int r = 0; r < 4; ++r) {                                              \
      float v = keep[r] ? sacc[st][r] : -1.0e9f;                               \
      vals[st][r] = v;                                                         \
      mloc = fmaxf(mloc, v);                                                   \
    }                                                                          \
  }                                                                            \
  LOAD_MASK(M8U, M32U, (C) + 2);   /* reload same set for chunk C+2 */         \
  mloc = fmaxf(mloc, __shfl_xor(mloc, 16));                                    \
  mloc = fmaxf(mloc, __shfl_xor(mloc, 32));                                    \
  /* defer-max: rescale only if some row's max grew by > 8 (log2 domain) */    \
  if (!__all(mloc <= m_run + 8.0f)) {                                          \
    float m_new = fmaxf(m_run, mloc);                                          \
    float alpha = __builtin_amdgcn_exp2f(m_run - m_new);                       \
    l_run *= alpha;                                                            \
    _Pragma("unroll")                                                          \
    for (int vt = 0; vt < 4; ++vt) {                                           \
      _Pragma("unroll")                                                        \
      for (int r = 0; r < 4; ++r) oacc[vt][r] *= alpha;                        \
    }                                                                          \
    m_run = m_new;                                                             \
  }                                                                            \
  float lsum = 0.f;                                                            \
  _Pragma("unroll")                                                            \
  for (int st = 0; st < 4; ++st) {                                             \
    bf16x4 pb;                                                                 \
    _Pragma("unroll")                                                          \
    for (int r = 0; r < 4; ++r) {                                              \
      float p = __builtin_amdgcn_exp2f(vals[st][r] - m_run);                   \
      lsum += p;                                                               \
      pb[r] = (__bf16)p;                                                       \
    }                                                                          \
    int off = (lq * 128 + (16 * st + 4 * g) * 2) ^ KSWZ(lq);                   \
    *(u16x4*)((char*)Psh[wave] + off) = __builtin_bit_cast(u16x4, pb);         \
  }                                                                            \
  lsum += __shfl_xor(lsum, 16);                                                \
  lsum += __shfl_xor(lsum, 32);                                                \
  l_run += lsum;                                                               \
  /* PV: O^T += V^T_tile · P^T */                                              \
  __builtin_amdgcn_s_setprio(1);                                               \
  _Pragma("unroll")                                                            \
  for (int ks = 0; ks < 2; ++ks) {                                             \
    int poff = (lq * 128 + (8 * g + 32 * ks) * 2) ^ KSWZ(lq);                  \
    bf16x8 pf = *(const bf16x8*)((const char*)Psh[wave] + poff);               \
    _Pragma("unroll")                                                          \
    for (int vt = 0; vt < 4; ++vt) {                                           \
      int vrow = lq + 16 * vt;                                                 \
      int voff = (vrow * 128 + (8 * g + 32 * ks) * 2) ^ VSWZ(vrow);            \
      bf16x8 vf = *(const bf16x8*)((const char*)Vsh[CUR] + voff);              \
      oacc[vt] = __builtin_amdgcn_mfma_f32_16x16x32_bf16(vf, pf, oacc[vt], 0, 0, 0); \
    }                                                                          \
  }                                                                            \
  __builtin_amdgcn_s_setprio(0);                                               \
  WRITE_KV((CUR) ^ 1, KPW, VPW);   /* drains loads issued one body ago */      \
  __syncthreads();                                                             \
}

  // prologue: chunk0 -> setA -> buf0; chunk1 -> setB (left in flight)
  PREFETCH_KV(0, kpA, vpA);
  LOAD_MASK(m8A, m32A, 0);
  PREFETCH_KV(1, kpB, vpB);
  LOAD_MASK(m8B, m32B, 1);
  WRITE_KV(0, kpA, vpA);
  __syncthreads();

  for (int cc = 0; cc < NCHUNK; cc += 2) {
    CHUNK_BODY(cc,     0, kpA, vpA, kpB, vpB, m8A, m32A);
    CHUNK_BODY(cc + 1, 1, kpB, vpB, kpA, vpA, m8B, m32B);
  }

  // epilogue: O = O^T(v,q)/l, store fp32 (lane: q=lq, v=16vt+4g+r)
  float inv_l = 1.0f / l_run;
  float* orow = Op + (size_t)qrow * VDIM;
#pragma unroll
  for (int vt = 0; vt < 4; ++vt) {
    f32x4 o;
#pragma unroll
    for (int r = 0; r < 4; ++r) o[r] = oacc[vt][r] * inv_l;
    *(f32x4*)(orow + 16 * vt + 4 * g) = o;
  }
#undef PREFETCH_KV
#undef WRITE_KV
#undef LOAD_MASK
#undef CHUNK_BODY
}

extern "C" void kernel_launch(void* const* d_in, const int* in_sizes, int n_in,
                              void* d_out, int out_size, void* d_ws, size_t ws_size,
                              hipStream_t stream) {
  const float* Qg = (const float*)d_in[0];
  const float* Kg = (const float*)d_in[1];
  const float* Vg = (const float*)d_in[2];
  const unsigned char* Mg = (const unsigned char*)d_in[3];
  float* Og = (float*)d_out;

  dim3 grid(NHEADS, QLEN / QBLK);   // 256 blocks; linear id % 8 == head -> head-per-XCD
  dim3 block(512);
  attn_fwd<true ><<<grid, block, 0, stream>>>(Qg, Kg, Vg, Mg, Og);   // u8 bool mask
  attn_fwd<false><<<grid, block, 0, stream>>>(Qg, Kg, Vg, Mg, Og);   // i32/f32 mask
}